// Round 1
// baseline (297.380 us; speedup 1.0000x reference)
//
#include <hip/hip_runtime.h>
#include <hip/hip_bf16.h>

// Problem constants (from reference setup_inputs): B=60, T=4, K=100, 1M docs.
#define T_DIM 4
#define K_DIM 100
#define NPER 400          // T*K entries per row
#define NDOCS 1000000
#define FILL_BLOCK 256
#define FILL_PER_THREAD 4
#define FILL_CHUNK (FILL_BLOCK * FILL_PER_THREAD)      // 4096
#define BLOCKS_PER_ROW ((NDOCS + FILL_CHUNK - 1) / FILL_CHUNK)  // 245

// -------- Kernel 1: per-row preprocessing (tiny) ------------------------
// Produces, per row b:
//   wsA[b*NPER + i]    = S[i] - i  (S = unique nonzero doc ids, ascending), i < nnz
//   wsHead[b*NPER + i] = i-th doc in (-score, id) order, i < nnz
//   wsNnz[b]           = nnz
//   out_pos[b]         = head[pos_positions[b]]   (positive_idx output)
__global__ __launch_bounds__(512) void rrf_prep_kernel(
    const int* __restrict__ idx, const float* __restrict__ rnk,
    const float* __restrict__ weight, const int* __restrict__ pos,
    int* __restrict__ wsA, int* __restrict__ wsHead, int* __restrict__ wsNnz,
    int* __restrict__ out_pos)
{
  const int b = blockIdx.x;
  const int tid = threadIdx.x;

  __shared__ int   ids[NPER];
  __shared__ float sc[NPER];
  __shared__ int   sid[NPER];
  __shared__ float ssc[NPER];
  __shared__ int   scan[512];
  __shared__ int   uid[NPER];
  __shared__ float usc[NPER];
  __shared__ int   head[NPER];
  __shared__ int   s_nnz;

  // Load ids + compute rrf scores: w_t / (60 + rank)
  if (tid < NPER) {
    ids[tid] = idx[b * NPER + tid];
    sc[tid]  = weight[tid / K_DIM] / (60.0f + rnk[b * NPER + tid]);
  }
  __syncthreads();

  // Rank-sort by (id, original position) -> groups duplicates adjacently,
  // duplicate scores kept in original-position order for summation.
  if (tid < NPER) {
    const int myid = ids[tid];
    int r = 0;
    for (int j = 0; j < NPER; ++j) {
      const int oj = ids[j];
      r += (oj < myid) || (oj == myid && j < tid);
    }
    sid[r] = myid;
    ssc[r] = sc[tid];
  }
  __syncthreads();

  // Leaders sum their duplicate run (in original-position order).
  int isLeader = 0;
  float mysum = 0.0f;
  if (tid < NPER) {
    isLeader = (tid == 0) || (sid[tid] != sid[tid - 1]);
    if (isLeader) {
      mysum = ssc[tid];
      for (int k = tid + 1; k < NPER && sid[k] == sid[tid]; ++k) mysum += ssc[k];
    }
  }
  scan[tid] = isLeader;
  __syncthreads();
  // Hillis-Steele inclusive scan over 512 slots (flags 0 beyond NPER).
  for (int off = 1; off < 512; off <<= 1) {
    int v = scan[tid];
    if (tid >= off) v += scan[tid - off];
    __syncthreads();
    scan[tid] = v;
    __syncthreads();
  }
  if (isLeader) {
    const int u = scan[tid] - 1;   // compacted slot; ascending id order preserved
    uid[u] = sid[tid];
    usc[u] = mysum;
  }
  if (tid == 0) s_nnz = scan[511];
  __syncthreads();
  const int nnz = s_nnz;

  // Rank-sort uniques by (-score, id asc) == stable argsort(-fused) order.
  if (tid < nnz) {
    const float si = usc[tid];
    const int   ii = uid[tid];
    int r2 = 0;
    for (int j = 0; j < nnz; ++j) {
      const float sj = usc[j];
      r2 += (sj > si) || (sj == si && uid[j] < ii);
    }
    head[r2] = ii;
  }
  __syncthreads();

  if (tid < nnz) {
    wsA[b * NPER + tid]    = uid[tid] - tid;  // A[i] = S[i]-i, non-decreasing
    wsHead[b * NPER + tid] = head[tid];
  }
  if (tid == 0) {
    wsNnz[b]   = nnz;
    out_pos[b] = head[pos[b]];   // pos in [0,5), nnz >= ~396 always
  }
}

// -------- Kernel 2: write order[B, NDOCS] (the 240 MB store) ------------
// order[p] = head[p] for p < nnz; else z = p - nnz, doc = z + count{A[i] <= z}.
__global__ __launch_bounds__(FILL_BLOCK) void rrf_fill_kernel(
    const int* __restrict__ wsA, const int* __restrict__ wsHead,
    const int* __restrict__ wsNnz, int* __restrict__ out)
{
  const int row   = blockIdx.x / BLOCKS_PER_ROW;
  const int chunk = blockIdx.x % BLOCKS_PER_ROW;
  const int tid   = threadIdx.x;

  __shared__ int A[NPER];
  __shared__ int H[NPER];
  __shared__ int s_nnz;
  for (int i = tid; i < NPER; i += FILL_BLOCK) {
    A[i] = wsA[row * NPER + i];      // entries >= nnz are garbage, never read
    H[i] = wsHead[row * NPER + i];
  }
  if (tid == 0) s_nnz = wsNnz[row];
  __syncthreads();
  const int nnz = s_nnz;

  const int lp0 = chunk * FILL_CHUNK + tid * FILL_PER_THREAD;
  if (lp0 >= NDOCS) return;   // only partial in last chunk; NDOCS%4==0 so all-or-none

  int v0, v1, v2, v3;
  if (lp0 >= nnz) {
    // Fast path: all 4 positions in the zero tail.
    int z = lp0 - nnz;
    int lo = 0, hi = nnz;
    while (lo < hi) { const int mid = (lo + hi) >> 1; if (A[mid] <= z) lo = mid + 1; else hi = mid; }
    int j = lo;                       // count{A[i] <= z}
    v0 = z + j;
    ++z; while (j < nnz && A[j] <= z) ++j; v1 = z + j;
    ++z; while (j < nnz && A[j] <= z) ++j; v2 = z + j;
    ++z; while (j < nnz && A[j] <= z) ++j; v3 = z + j;
  } else {
    // Slow path: only the first block of each row ever takes this.
    int vv[4];
    for (int k = 0; k < 4; ++k) {
      const int p = lp0 + k;
      if (p < nnz) vv[k] = H[p];
      else {
        const int z = p - nnz;
        int lo = 0, hi = nnz;
        while (lo < hi) { const int mid = (lo + hi) >> 1; if (A[mid] <= z) lo = mid + 1; else hi = mid; }
        vv[k] = z + lo;
      }
    }
    v0 = vv[0]; v1 = vv[1]; v2 = vv[2]; v3 = vv[3];
  }

  // Coalesced 16B/lane store; row*NDOCS and lp0 both multiples of 4 -> aligned.
  *reinterpret_cast<int4*>(out + (long long)row * NDOCS + lp0) = make_int4(v0, v1, v2, v3);
}

extern "C" void kernel_launch(void* const* d_in, const int* in_sizes, int n_in,
                              void* d_out, int out_size, void* d_ws, size_t ws_size,
                              hipStream_t stream) {
  const int*   idx    = (const int*)d_in[0];    // [B,T,K] int32
  const float* rnk    = (const float*)d_in[1];  // [B,T,K] f32
  const float* weight = (const float*)d_in[2];  // [T] f32
  const int*   pos    = (const int*)d_in[3];    // [B] int32
  const int B = in_sizes[3];                    // 60

  int* out = (int*)d_out;                       // order[B*NDOCS] ++ positive_idx[B], int32
  int* ws  = (int*)d_ws;
  int* wsA    = ws;                             // B*NPER ints
  int* wsHead = ws + (size_t)B * NPER;          // B*NPER ints
  int* wsNnz  = ws + (size_t)2 * B * NPER;      // B ints   (~192 KB total)

  rrf_prep_kernel<<<B, 512, 0, stream>>>(idx, rnk, weight, pos,
                                         wsA, wsHead, wsNnz,
                                         out + (size_t)B * NDOCS);
  rrf_fill_kernel<<<B * BLOCKS_PER_ROW, FILL_BLOCK, 0, stream>>>(wsA, wsHead, wsNnz, out);
}